// Round 1
// baseline (930.319 us; speedup 1.0000x reference)
//
#include <hip/hip_runtime.h>
#include <stdint.h>

typedef unsigned int u32;
typedef unsigned short u16;
typedef float f32x4 __attribute__((ext_vector_type(4)));
typedef short short8 __attribute__((ext_vector_type(8)));
typedef unsigned short ushort8 __attribute__((ext_vector_type(8)));

#define HID 128
#define MT  16        // batch rows per workgroup
#define NWG 512       // 8192 / 16
#define LD  136       // padded LDS plane stride (elements); 272B rows keep 16B alignment

// ---- workspace byte offsets ----
#define OFF_Y0    0         // 16384 f32
#define OFF_Y1    65536
#define OFF_KA    131072    // k1 cache buffers (FSAL reuse)
#define OFF_KB    196608
#define OFF_PART  262144    // 512 f32 partial err^2 sums
#define OFF_CNT   264192    // 64 u32 arrival counters
#define OFF_SCAL  264448    // f32 h, f32 tc, u32 yidx, u32 kidx
#define OFF_W2TH  266240    // 128x128 bf16 (transposed [n][k]) hi
#define OFF_W2TL  299008
#define OFF_W3TH  331776
#define OFF_W3TL  364544
#define OFF_W1    397312    // [2][128] f32
#define OFF_B1    398336
#define OFF_B2    398848
#define OFF_B3    399360
#define OFF_W4T   399872    // [2][128] f32 (transposed)
#define OFF_B4    400896

// ---- Dormand-Prince tableau (double -> f32, matches JAX constant folding) ----
constexpr float CA21 = (float)(1.0/5.0);
constexpr float CA31 = (float)(3.0/40.0),   CA32 = (float)(9.0/40.0);
constexpr float CA41 = (float)(44.0/45.0),  CA42 = (float)(-56.0/15.0), CA43 = (float)(32.0/9.0);
constexpr float CA51 = (float)(19372.0/6561.0), CA52 = (float)(-25360.0/2187.0);
constexpr float CA53 = (float)(64448.0/6561.0), CA54 = (float)(-212.0/729.0);
constexpr float CA61 = (float)(9017.0/3168.0),  CA62 = (float)(-355.0/33.0);
constexpr float CA63 = (float)(46732.0/5247.0), CA64 = (float)(49.0/176.0), CA65 = (float)(-5103.0/18656.0);
constexpr float CB1 = (float)(35.0/384.0), CB3 = (float)(500.0/1113.0), CB4 = (float)(125.0/192.0);
constexpr float CB5 = (float)(-2187.0/6784.0), CB6 = (float)(11.0/84.0);
constexpr float CE1 = (float)(35.0/384.0 - 5179.0/57600.0);
constexpr float CE3 = (float)(500.0/1113.0 - 7571.0/16695.0);
constexpr float CE4 = (float)(125.0/192.0 - 393.0/640.0);
constexpr float CE5 = (float)(-2187.0/6784.0 + 92097.0/339200.0);
constexpr float CE6 = (float)(11.0/84.0 - 187.0/2100.0);
constexpr float CE7 = (float)(-1.0/40.0);

__device__ __forceinline__ u16 f2bf(float x) {
  u32 u = __builtin_bit_cast(u32, x);
  u32 r = (u + 0x7FFFu + ((u >> 16) & 1u)) >> 16;
  return (u16)r;
}
__device__ __forceinline__ float bf2f(u16 b) {
  u32 u = ((u32)b) << 16;
  return __builtin_bit_cast(float, u);
}
__device__ __forceinline__ float eluf(float x) {
  return x > 0.f ? x : (__expf(x) - 1.f);
}

// ---------------------------------------------------------------------------
// Prologue: weight transpose + hi/lo bf16 split into ws, x0 copies, scalars.
// ---------------------------------------------------------------------------
__global__ void prologue(const float* __restrict__ x0, const float* __restrict__ t,
                         const float* __restrict__ W1, const float* __restrict__ b1,
                         const float* __restrict__ W2, const float* __restrict__ b2,
                         const float* __restrict__ W3, const float* __restrict__ b3,
                         const float* __restrict__ W4, const float* __restrict__ b4,
                         float* __restrict__ ws, float* __restrict__ out)
{
  int gid = blockIdx.x * blockDim.x + threadIdx.x;   // 64*256 = 16384
  // y buffers + first output point
  float xv = x0[gid];
  out[gid] = xv;
  ws[OFF_Y0/4 + gid] = xv;
  // W2 / W3: transpose to [n][k] and split hi/lo
  {
    int k = gid >> 7, j = gid & 127;
    u16* w2th = (u16*)((char*)ws + OFF_W2TH);
    u16* w2tl = (u16*)((char*)ws + OFF_W2TL);
    u16* w3th = (u16*)((char*)ws + OFF_W3TH);
    u16* w3tl = (u16*)((char*)ws + OFF_W3TL);
    float w = W2[gid];
    u16 hb = f2bf(w);
    w2th[j*HID + k] = hb;
    w2tl[j*HID + k] = f2bf(w - bf2f(hb));
    w = W3[gid];
    hb = f2bf(w);
    w3th[j*HID + k] = hb;
    w3tl[j*HID + k] = f2bf(w - bf2f(hb));
  }
  if (gid < 256) ws[OFF_W1/4 + gid] = W1[gid];
  if (gid < 128) {
    ws[OFF_B1/4 + gid] = b1[gid];
    ws[OFF_B2/4 + gid] = b2[gid];
    ws[OFF_B3/4 + gid] = b3[gid];
  }
  if (gid < 256) { int k = gid >> 1, c = gid & 1; ws[OFF_W4T/4 + c*HID + k] = W4[gid]; }
  if (gid < 2)  ws[OFF_B4/4 + gid] = b4[gid];
  if (gid < 64) ((u32*)((char*)ws + OFF_CNT))[gid] = 0u;
  if (gid == 0) {
    ws[OFF_SCAL/4 + 0] = 0.5f * (t[1] - t[0]);   // h0
    ws[OFF_SCAL/4 + 1] = t[0];                   // tc
    ((u32*)(ws + OFF_SCAL/4))[2] = 0u;           // yidx
    ((u32*)(ws + OFF_SCAL/4))[3] = 0u;           // kidx
  }
}

// ---------------------------------------------------------------------------
// One adaptive DOPRI5 substep for the whole batch (+ global controller).
// ---------------------------------------------------------------------------
template<int FIRST>
__global__ __launch_bounds__(256, 2)
void ode_step(const float* __restrict__ t_arr, float* __restrict__ ws,
              int iv, int s, int step_id)
{
  const int tid  = threadIdx.x;
  const int wg   = blockIdx.x;
  const int lane = tid & 63;
  const int wave = tid >> 6;

  float* scal = ws + OFF_SCAL/4;
  u32*  scalu = (u32*)scal;
  const float h_in  = scal[0];
  const float tc_in = scal[1];
  const u32 yidx = scalu[2];
  const u32 kidx = scalu[3];
  const float t0 = t_arr[iv];
  const float t1 = t_arr[iv + 1];
  const float tcur = (s == 0) ? t0 : tc_in;
  const float rem  = t1 - tcur;
  const bool  done = (rem <= 1e-9f);
  const float h    = done ? h_in : fminf(h_in, rem);   // h_eff

  float* ybuf  = ws + (yidx ? OFF_Y1 : OFF_Y0) / 4;
  float* ybufN = ws + (yidx ? OFF_Y0 : OFF_Y1) / 4;
  float* kbuf  = ws + (kidx ? OFF_KB : OFF_KA) / 4;
  float* kbufN = ws + (kidx ? OFF_KA : OFF_KB) / 4;

  __shared__ __align__(16) u16 Ahi[2][MT][LD];
  __shared__ __align__(16) u16 Alo[2][MT][LD];
  __shared__ float ysL[MT][2];
  __shared__ float yL [MT][2];
  __shared__ float y5L[MT][2];
  __shared__ float kS [7][MT][2];
  __shared__ float red[256];
  __shared__ float Wsm[642];   // [0..255]=W1, [256..383]=b1, [384..639]=W4t, [640..641]=b4
  __shared__ u32 flagL;

  float errsq = 0.f;

  if (!done) {
    // ---- resident weight B-fragments (bf16 hi/lo) ----
    const u16* w2th = (const u16*)((const char*)ws + OFF_W2TH);
    const u16* w2tl = (const u16*)((const char*)ws + OFF_W2TL);
    const u16* w3th = (const u16*)((const char*)ws + OFF_W3TH);
    const u16* w3tl = (const u16*)((const char*)ws + OFF_W3TL);
    short8 W2H[2][4], W2L[2][4], W3H[2][4], W3L[2][4];
    const int colbase = wave * 32 + (lane & 15);
    const int krow = (lane >> 4) * 8;
#pragma unroll
    for (int nt = 0; nt < 2; ++nt)
#pragma unroll
      for (int ks = 0; ks < 4; ++ks) {
        int off = (colbase + nt*16) * HID + ks*32 + krow;
        W2H[nt][ks] = *(const short8*)(w2th + off);
        W2L[nt][ks] = *(const short8*)(w2tl + off);
        W3H[nt][ks] = *(const short8*)(w3th + off);
        W3L[nt][ks] = *(const short8*)(w3tl + off);
      }
    float b2v[2], b3v[2];
    {
      const float* b2g = ws + OFF_B2/4;
      const float* b3g = ws + OFF_B3/4;
      b2v[0] = b2g[colbase];      b2v[1] = b2g[colbase + 16];
      b3v[0] = b3g[colbase];      b3v[1] = b3g[colbase + 16];
    }
    // stage small weights to LDS
    Wsm[tid]       = (ws + OFF_W1/4)[tid];
    Wsm[384 + tid] = (ws + OFF_W4T/4)[tid];
    if (tid < 128) Wsm[256 + tid] = (ws + OFF_B1/4)[tid];
    if (tid < 2)   Wsm[640 + tid] = (ws + OFF_B4/4)[tid];

    // load y (and cached k1)
    if (tid < 32) {
      float yv = ybuf[wg*32 + tid];
      yL[tid >> 1][tid & 1] = yv;
      if (FIRST) ysL[tid >> 1][tid & 1] = yv;
      else       kS[0][tid >> 1][tid & 1] = kbuf[wg*32 + tid];
    }
    __syncthreads();

    // layer 2/3 GEMM: src plane -> dst plane (elu + hi/lo split on store)
    auto mm_layer = [&](const u16 (*Shi)[LD], const u16 (*Slo)[LD],
                        u16 (*Dhi)[LD], u16 (*Dlo)[LD],
                        short8 (&WH)[2][4], short8 (&WL)[2][4],
                        float bv0, float bv1) {
      f32x4 c0 = {bv0, bv0, bv0, bv0};
      f32x4 c1 = {bv1, bv1, bv1, bv1};
      const int ar = lane & 15;
      const int ak = (lane >> 4) * 8;
#pragma unroll
      for (int ks = 0; ks < 4; ++ks) {
        short8 ah = *(const short8*)&Shi[ar][ks*32 + ak];
        short8 al = *(const short8*)&Slo[ar][ks*32 + ak];
        c0 = __builtin_amdgcn_mfma_f32_16x16x32_bf16(ah, WH[0][ks], c0, 0, 0, 0);
        c0 = __builtin_amdgcn_mfma_f32_16x16x32_bf16(ah, WL[0][ks], c0, 0, 0, 0);
        c0 = __builtin_amdgcn_mfma_f32_16x16x32_bf16(al, WH[0][ks], c0, 0, 0, 0);
        c1 = __builtin_amdgcn_mfma_f32_16x16x32_bf16(ah, WH[1][ks], c1, 0, 0, 0);
        c1 = __builtin_amdgcn_mfma_f32_16x16x32_bf16(ah, WL[1][ks], c1, 0, 0, 0);
        c1 = __builtin_amdgcn_mfma_f32_16x16x32_bf16(al, WH[1][ks], c1, 0, 0, 0);
      }
      const int colA = wave * 32 + (lane & 15);
#pragma unroll
      for (int r = 0; r < 4; ++r) {
        int row = (lane >> 4) * 4 + r;
        float v0 = eluf(c0[r]);
        u16 h0 = f2bf(v0);
        Dhi[row][colA] = h0;
        Dlo[row][colA] = f2bf(v0 - bf2f(h0));
        float v1 = eluf(c1[r]);
        u16 h1 = f2bf(v1);
        Dhi[row][colA + 16] = h1;
        Dlo[row][colA + 16] = f2bf(v1 - bf2f(h1));
      }
    };

    // full dynamics eval: ysL -> kS[kslot]
    auto feval = [&](int kslot, bool wknew, bool wk1) {
      // L1: (2 -> 128), VALU
      {
        int m  = tid >> 4;
        int j0 = (tid & 15) * 8;
        float y0 = ysL[m][0], y1 = ysL[m][1];
        ushort8 hh, hl;
#pragma unroll
        for (int jj = 0; jj < 8; ++jj) {
          int j = j0 + jj;
          float v = fmaf(y1, Wsm[HID + j], fmaf(y0, Wsm[j], Wsm[256 + j]));
          v = eluf(v);
          u16 hb = f2bf(v);
          hh[jj] = hb;
          hl[jj] = f2bf(v - bf2f(hb));
        }
        *(ushort8*)&Ahi[0][m][j0] = hh;
        *(ushort8*)&Alo[0][m][j0] = hl;
      }
      __syncthreads();
      mm_layer(Ahi[0], Alo[0], Ahi[1], Alo[1], W2H, W2L, b2v[0], b2v[1]);   // L2
      __syncthreads();
      mm_layer(Ahi[1], Alo[1], Ahi[0], Alo[0], W3H, W3L, b3v[0], b3v[1]);   // L3
      __syncthreads();
      // L4: (128 -> 2), VALU split-K over 8 chunks
      {
        int m  = tid & 15;
        int c4 = (tid >> 4) & 1;
        int ch = tid >> 5;
        int k0 = ch * 16;
        ushort8 uh0 = *(const ushort8*)&Ahi[0][m][k0];
        ushort8 uh1 = *(const ushort8*)&Ahi[0][m][k0 + 8];
        ushort8 ul0 = *(const ushort8*)&Alo[0][m][k0];
        ushort8 ul1 = *(const ushort8*)&Alo[0][m][k0 + 8];
        float p = 0.f;
#pragma unroll
        for (int i = 0; i < 8; ++i) {
          float hv0 = bf2f(uh0[i]) + bf2f(ul0[i]);
          float hv1 = bf2f(uh1[i]) + bf2f(ul1[i]);
          p = fmaf(hv0, Wsm[384 + c4*HID + k0 + i],     p);
          p = fmaf(hv1, Wsm[384 + c4*HID + k0 + 8 + i], p);
        }
        red[tid] = p;
      }
      __syncthreads();
      if (tid < 32) {
        int m = tid & 15, c4 = tid >> 4;
        int base = (c4 << 4) | m;
        float ssum = Wsm[640 + c4];
#pragma unroll
        for (int ch = 0; ch < 8; ++ch) ssum += red[base + (ch << 5)];
        kS[kslot][m][c4] = ssum;
        int gi = wg*32 + m*2 + c4;
        if (wknew) kbufN[gi] = ssum;              // k7 -> next k1 (accept case)
        if (FIRST && wk1) kbuf[gi] = ssum;        // very first k1 (reject case)
      }
      __syncthreads();
    };

    if (FIRST) feval(0, false, true);             // k1 = f(y)

    if (tid < 32) { int m = tid >> 1, c = tid & 1;
      ysL[m][c] = fmaf(h, CA21 * kS[0][m][c], yL[m][c]); }
    __syncthreads();
    feval(1, false, false);                       // k2

    if (tid < 32) { int m = tid >> 1, c = tid & 1;
      float a = CA31*kS[0][m][c] + CA32*kS[1][m][c];
      ysL[m][c] = fmaf(h, a, yL[m][c]); }
    __syncthreads();
    feval(2, false, false);                       // k3

    if (tid < 32) { int m = tid >> 1, c = tid & 1;
      float a = CA41*kS[0][m][c] + CA42*kS[1][m][c] + CA43*kS[2][m][c];
      ysL[m][c] = fmaf(h, a, yL[m][c]); }
    __syncthreads();
    feval(3, false, false);                       // k4

    if (tid < 32) { int m = tid >> 1, c = tid & 1;
      float a = CA51*kS[0][m][c] + CA52*kS[1][m][c] + CA53*kS[2][m][c] + CA54*kS[3][m][c];
      ysL[m][c] = fmaf(h, a, yL[m][c]); }
    __syncthreads();
    feval(4, false, false);                       // k5

    if (tid < 32) { int m = tid >> 1, c = tid & 1;
      float a = CA61*kS[0][m][c] + CA62*kS[1][m][c] + CA63*kS[2][m][c] + CA64*kS[3][m][c] + CA65*kS[4][m][c];
      ysL[m][c] = fmaf(h, a, yL[m][c]); }
    __syncthreads();
    feval(5, false, false);                       // k6

    if (tid < 32) { int m = tid >> 1, c = tid & 1;
      float a = CB1*kS[0][m][c] + CB3*kS[2][m][c] + CB4*kS[3][m][c] + CB5*kS[4][m][c] + CB6*kS[5][m][c];
      float y5 = fmaf(h, a, yL[m][c]);
      y5L[m][c] = y5;
      ysL[m][c] = y5;
      ybufN[wg*32 + tid] = y5;                    // candidate next y
    }
    __syncthreads();
    feval(6, true, false);                        // k7 = f(y5) (FSAL)

    // local error^2 partial
    if (tid < 32) { int m = tid >> 1, c = tid & 1;
      float e = CE1*kS[0][m][c] + CE3*kS[2][m][c] + CE4*kS[3][m][c]
              + CE5*kS[4][m][c] + CE6*kS[5][m][c] + CE7*kS[6][m][c];
      e *= h;
      float tol = 1e-4f + 1e-3f * fmaxf(fabsf(yL[m][c]), fabsf(y5L[m][c]));
      float r = e / tol;
      red[tid] = r * r;
    }
    __syncthreads();
    if (tid == 0) {
      float sm = 0.f;
#pragma unroll
      for (int i = 0; i < 32; ++i) sm += red[i];
      errsq = sm;
    }
  } // !done

  // ---- global deterministic reduction + controller (last-WG pattern) ----
  float* part = (float*)((char*)ws + OFF_PART);
  if (tid == 0) {
    __hip_atomic_store(part + wg, errsq, __ATOMIC_RELAXED, __HIP_MEMORY_SCOPE_AGENT);
    __threadfence();
    u32 old = atomicAdd((u32*)((char*)ws + OFF_CNT) + step_id, 1u);
    flagL = (old == (u32)(NWG - 1)) ? 1u : 0u;
  }
  __syncthreads();
  if (flagL) {
    __threadfence();
    float v = __hip_atomic_load(part + tid,       __ATOMIC_RELAXED, __HIP_MEMORY_SCOPE_AGENT)
            + __hip_atomic_load(part + tid + 256, __ATOMIC_RELAXED, __HIP_MEMORY_SCOPE_AGENT);
    red[tid] = v;
    __syncthreads();
    for (int st = 128; st >= 1; st >>= 1) {
      if (tid < st) red[tid] += red[tid + st];
      __syncthreads();
    }
    if (tid == 0) {
      float err_norm = sqrtf(red[0] / 16384.f);
      bool accept = (err_norm <= 1.0f) && !done;
      if (accept) { scalu[2] = yidx ^ 1u; scalu[3] = kidx ^ 1u; }
      scal[1] = accept ? (tcur + h) : tcur;
      float factor = fminf(10.f, fmaxf(0.2f, 0.9f * powf(fmaxf(err_norm, 1e-10f), -0.2f)));
      scal[0] = done ? h_in : h * factor;
    }
  }
}

// ---------------------------------------------------------------------------
// Copy current y into the output slice for one time point.
// ---------------------------------------------------------------------------
__global__ void outcopy(float* __restrict__ out, const float* __restrict__ ws, int iv)
{
  int gid = blockIdx.x * blockDim.x + threadIdx.x;   // 16*256 = 4096 float4s
  u32 yidx = ((const u32*)(ws + OFF_SCAL/4))[2];
  const f32x4* src = (const f32x4*)(ws + (yidx ? OFF_Y1 : OFF_Y0) / 4);
  f32x4* dst = (f32x4*)(out + (size_t)(iv + 1) * 16384);
  dst[gid] = src[gid];
}

extern "C" void kernel_launch(void* const* d_in, const int* in_sizes, int n_in,
                              void* d_out, int out_size, void* d_ws, size_t ws_size,
                              hipStream_t stream)
{
  const float* x0 = (const float*)d_in[0];
  const float* t  = (const float*)d_in[1];
  const float* W1 = (const float*)d_in[2];
  const float* b1 = (const float*)d_in[3];
  const float* W2 = (const float*)d_in[4];
  const float* b2 = (const float*)d_in[5];
  const float* W3 = (const float*)d_in[6];
  const float* b3 = (const float*)d_in[7];
  const float* W4 = (const float*)d_in[8];
  const float* b4 = (const float*)d_in[9];
  float* out = (float*)d_out;
  float* ws  = (float*)d_ws;

  prologue<<<64, 256, 0, stream>>>(x0, t, W1, b1, W2, b2, W3, b3, W4, b4, ws, out);

  int step = 0;
  for (int iv = 0; iv < 7; ++iv) {
    for (int s = 0; s < 8; ++s) {
      if (step == 0) ode_step<1><<<NWG, 256, 0, stream>>>(t, ws, iv, s, step);
      else           ode_step<0><<<NWG, 256, 0, stream>>>(t, ws, iv, s, step);
      ++step;
    }
    outcopy<<<16, 256, 0, stream>>>(out, ws, iv);
  }
}

// Round 3
// 298.516 us; speedup vs baseline: 3.1165x; 3.1165x over previous
//
#include <hip/hip_runtime.h>
#include <stdint.h>

typedef unsigned int u32;
typedef unsigned short u16;
typedef float f32x4 __attribute__((ext_vector_type(4)));
typedef short short8 __attribute__((ext_vector_type(8)));
typedef unsigned short ushort8 __attribute__((ext_vector_type(8)));

#define HID 128
#define MT  32        // batch rows per workgroup
#define NWG 256       // 8192 / 32 -- co-resident even at 1 block/CU
#define LD  136

// ---- ws byte offsets ----
#define OFF_PART  0         // 256 f32
#define OFF_CNT   1024      // 64 u32
#define OFF_HPAY  1280      // 64 f32
#define OFF_FLAG  1536      // 64 u32
#define OFF_WPACK 2048      // 644 f32: W1(256), b1(128), b2(128), b3(128), b4(2)
#define OFF_W2TH  5120      // 128x128 bf16 [n][k] hi
#define OFF_W2TL  37888
#define OFF_W3TH  70656
#define OFF_W3TL  103424
#define OFF_W4FH  136192    // 16x128 bf16 [c][k], cols 2..15 zero
#define OFF_W4FL  140288

constexpr float CA21 = (float)(1.0/5.0);
constexpr float CA31 = (float)(3.0/40.0),   CA32 = (float)(9.0/40.0);
constexpr float CA41 = (float)(44.0/45.0),  CA42 = (float)(-56.0/15.0), CA43 = (float)(32.0/9.0);
constexpr float CA51 = (float)(19372.0/6561.0), CA52 = (float)(-25360.0/2187.0);
constexpr float CA53 = (float)(64448.0/6561.0), CA54 = (float)(-212.0/729.0);
constexpr float CA61 = (float)(9017.0/3168.0),  CA62 = (float)(-355.0/33.0);
constexpr float CA63 = (float)(46732.0/5247.0), CA64 = (float)(49.0/176.0), CA65 = (float)(-5103.0/18656.0);
constexpr float CB1 = (float)(35.0/384.0), CB3 = (float)(500.0/1113.0), CB4 = (float)(125.0/192.0);
constexpr float CB5 = (float)(-2187.0/6784.0), CB6 = (float)(11.0/84.0);
constexpr float CE1 = (float)(35.0/384.0 - 5179.0/57600.0);
constexpr float CE3 = (float)(500.0/1113.0 - 7571.0/16695.0);
constexpr float CE4 = (float)(125.0/192.0 - 393.0/640.0);
constexpr float CE5 = (float)(-2187.0/6784.0 + 92097.0/339200.0);
constexpr float CE6 = (float)(11.0/84.0 - 187.0/2100.0);
constexpr float CE7 = (float)(-1.0/40.0);

template<int N> struct IC { static constexpr int v = N; };

__device__ __forceinline__ u16 f2bf(float x) {
  u32 u = __builtin_bit_cast(u32, x);
  u32 r = (u + 0x7FFFu + ((u >> 16) & 1u)) >> 16;
  return (u16)r;
}
__device__ __forceinline__ float bf2f(u16 b) {
  u32 u = ((u32)b) << 16;
  return __builtin_bit_cast(float, u);
}
__device__ __forceinline__ float eluf(float x) {
  return x > 0.f ? x : (__expf(x) - 1.f);
}

// ---------------------------------------------------------------------------
// Prologue: weight prep into ws, x0 -> out[0], zero sync state.
// ---------------------------------------------------------------------------
__global__ void prologue(const float* __restrict__ x0, const float* __restrict__ t,
                         const float* __restrict__ W1, const float* __restrict__ b1,
                         const float* __restrict__ W2, const float* __restrict__ b2,
                         const float* __restrict__ W3, const float* __restrict__ b3,
                         const float* __restrict__ W4, const float* __restrict__ b4,
                         float* __restrict__ ws, float* __restrict__ out)
{
  int gid = blockIdx.x * blockDim.x + threadIdx.x;   // 64*256 = 16384
  out[gid] = x0[gid];
  {
    int k = gid >> 7, j = gid & 127;
    u16* w2th = (u16*)((char*)ws + OFF_W2TH);
    u16* w2tl = (u16*)((char*)ws + OFF_W2TL);
    u16* w3th = (u16*)((char*)ws + OFF_W3TH);
    u16* w3tl = (u16*)((char*)ws + OFF_W3TL);
    float w = W2[gid];
    u16 hb = f2bf(w);
    w2th[j*HID + k] = hb;
    w2tl[j*HID + k] = f2bf(w - bf2f(hb));
    w = W3[gid];
    hb = f2bf(w);
    w3th[j*HID + k] = hb;
    w3tl[j*HID + k] = f2bf(w - bf2f(hb));
  }
  if (gid < 2048) {           // W4 fragments: [c 0..15][k 0..127], c>=2 zero
    int c = gid >> 7, k = gid & 127;
    float w = (c < 2) ? W4[k*2 + c] : 0.f;
    u16 hb = f2bf(w);
    ((u16*)((char*)ws + OFF_W4FH))[gid] = hb;
    ((u16*)((char*)ws + OFF_W4FL))[gid] = f2bf(w - bf2f(hb));
  }
  float* wp = ws + OFF_WPACK/4;
  if (gid < 256) wp[gid] = W1[gid];
  if (gid < 128) {
    wp[256 + gid] = b1[gid];
    wp[384 + gid] = b2[gid];
    wp[512 + gid] = b3[gid];
  }
  if (gid < 2)  wp[640 + gid] = b4[gid];
  if (gid < 64) {
    ((u32*)((char*)ws + OFF_CNT))[gid]  = 0u;
    ((u32*)((char*)ws + OFF_FLAG))[gid] = 0u;
  }
}

// ---------------------------------------------------------------------------
// Persistent solver (plain launch; 256 WGs co-resident by construction).
// ---------------------------------------------------------------------------
__global__ __launch_bounds__(256, 2)
void solver(const float* __restrict__ x0, const float* __restrict__ t_arr,
            float* __restrict__ ws, float* __restrict__ out)
{
  const int tid  = threadIdx.x;
  const int wg   = blockIdx.x;
  const int lane = tid & 63;
  const int wave = tid >> 6;

  __shared__ __align__(16) u16 Ahi[2][MT][LD];
  __shared__ __align__(16) u16 Alo[2][MT][LD];
  __shared__ __align__(16) u16 W4F[2][16][HID];
  __shared__ __align__(16) float Wsm[644];
  __shared__ float kS[7][MT][2];
  __shared__ float yL[MT][2];
  __shared__ float ysL[MT][2];
  __shared__ float y5L[MT][2];
  __shared__ float red[256];
  __shared__ u32 bcF;
  __shared__ float bcH;
  __shared__ u32 flagL;

  // ---- one-time setup ----
  {
    const float* wp = ws + OFF_WPACK/4;
    Wsm[tid]       = wp[tid];
    Wsm[256 + tid] = wp[256 + tid];
    if (tid < 132) Wsm[512 + tid] = wp[512 + tid];
    const ushort8* h8 = (const ushort8*)((const char*)ws + OFF_W4FH);
    const ushort8* l8 = (const ushort8*)((const char*)ws + OFF_W4FL);
    ((ushort8*)&W4F[0][0][0])[tid] = h8[tid];
    ((ushort8*)&W4F[1][0][0])[tid] = l8[tid];
  }
  if (tid < 64) yL[tid >> 1][tid & 1] = x0[wg*64 + tid];

  // resident weight B-fragments (bf16 hi/lo): 128 VGPRs
  const u16* w2th = (const u16*)((const char*)ws + OFF_W2TH);
  const u16* w2tl = (const u16*)((const char*)ws + OFF_W2TL);
  const u16* w3th = (const u16*)((const char*)ws + OFF_W3TH);
  const u16* w3tl = (const u16*)((const char*)ws + OFF_W3TL);
  short8 W2H[2][4], W2L[2][4], W3H[2][4], W3L[2][4];
  const int colbase = wave * 32 + (lane & 15);
  const int krow = (lane >> 4) * 8;
#pragma unroll
  for (int nt = 0; nt < 2; ++nt)
#pragma unroll
    for (int ks = 0; ks < 4; ++ks) {
      int off = (colbase + nt*16) * HID + ks*32 + krow;
      W2H[nt][ks] = *(const short8*)(w2th + off);
      W2L[nt][ks] = *(const short8*)(w2tl + off);
      W3H[nt][ks] = *(const short8*)(w3th + off);
      W3L[nt][ks] = *(const short8*)(w3tl + off);
    }
  __syncthreads();
  const float b2v0 = Wsm[384 + colbase], b2v1 = Wsm[384 + colbase + 16];
  const float b3v0 = Wsm[512 + colbase], b3v1 = Wsm[512 + colbase + 16];

  float* part = (float*)((char*)ws + OFF_PART);
  u32*  cnt   = (u32*) ((char*)ws + OFF_CNT);
  float* hpay = (float*)((char*)ws + OFF_HPAY);
  u32*  flg   = (u32*) ((char*)ws + OFF_FLAG);

  float h = 0.5f * (t_arr[1] - t_arr[0]);
  float heff = h;

  // L2/L3 GEMM (all 4 waves, 2 row-tiles each): plane sp -> plane dp
  auto mm = [&](int sp, int dp, short8 (&WH)[2][4], short8 (&WL)[2][4],
                float bv0, float bv1) {
    const int ar = lane & 15;
    const int ak = (lane >> 4) * 8;
    f32x4 acc[2][2][3];
#pragma unroll
    for (int rt = 0; rt < 2; ++rt) {
      acc[rt][0][0] = {bv0,bv0,bv0,bv0}; acc[rt][0][1] = {0,0,0,0}; acc[rt][0][2] = {0,0,0,0};
      acc[rt][1][0] = {bv1,bv1,bv1,bv1}; acc[rt][1][1] = {0,0,0,0}; acc[rt][1][2] = {0,0,0,0};
    }
#pragma unroll
    for (int ks = 0; ks < 4; ++ks) {
#pragma unroll
      for (int rt = 0; rt < 2; ++rt) {
        short8 ah = *(const short8*)&Ahi[sp][rt*16 + ar][ks*32 + ak];
        short8 al = *(const short8*)&Alo[sp][rt*16 + ar][ks*32 + ak];
#pragma unroll
        for (int ct = 0; ct < 2; ++ct) {
          acc[rt][ct][0] = __builtin_amdgcn_mfma_f32_16x16x32_bf16(ah, WH[ct][ks], acc[rt][ct][0], 0, 0, 0);
          acc[rt][ct][1] = __builtin_amdgcn_mfma_f32_16x16x32_bf16(ah, WL[ct][ks], acc[rt][ct][1], 0, 0, 0);
          acc[rt][ct][2] = __builtin_amdgcn_mfma_f32_16x16x32_bf16(al, WH[ct][ks], acc[rt][ct][2], 0, 0, 0);
        }
      }
    }
    const int colA = wave * 32 + (lane & 15);
#pragma unroll
    for (int rt = 0; rt < 2; ++rt)
#pragma unroll
      for (int ct = 0; ct < 2; ++ct)
#pragma unroll
        for (int r = 0; r < 4; ++r) {
          int row = rt*16 + (lane >> 4) * 4 + r;
          float v = eluf(acc[rt][ct][0][r] + acc[rt][ct][1][r] + acc[rt][ct][2][r]);
          u16 hb = f2bf(v);
          Ahi[dp][row][colA + ct*16] = hb;
          Alo[dp][row][colA + ct*16] = f2bf(v - bf2f(hb));
        }
  };

  // full dynamics eval ysL -> kS[SLOT], with fused stage-combine in phase D
  auto feval = [&](auto SC) {
    constexpr int SLOT = decltype(SC)::v;
    // Phase A: L1 (2 -> 128), VALU; thread -> (row m, 16 cols)
    {
      int m  = tid >> 3;
      int j0 = (tid & 7) * 16;
      float y0 = ysL[m][0], y1 = ysL[m][1];
#pragma unroll
      for (int g = 0; g < 2; ++g) {
        ushort8 hh, hl;
#pragma unroll
        for (int jj = 0; jj < 8; ++jj) {
          int j = j0 + g*8 + jj;
          float v = fmaf(y1, Wsm[128 + j], fmaf(y0, Wsm[j], Wsm[256 + j]));
          v = eluf(v);
          u16 hb = f2bf(v);
          hh[jj] = hb; hl[jj] = f2bf(v - bf2f(hb));
        }
        *(ushort8*)&Ahi[0][m][j0 + g*8] = hh;
        *(ushort8*)&Alo[0][m][j0 + g*8] = hl;
      }
    }
    __syncthreads();
    mm(0, 1, W2H, W2L, b2v0, b2v1);   // L2
    __syncthreads();
    mm(1, 0, W3H, W3L, b3v0, b3v1);   // L3
    __syncthreads();
    // Phase D: L4 via MFMA + fused stage combine (waves 0,1 = row-tiles 0,1)
    if (wave < 2) {
      const int ar = lane & 15;
      const int ak = (lane >> 4) * 8;
      f32x4 ch = {0,0,0,0}, cm = {0,0,0,0}, cl = {0,0,0,0};
#pragma unroll
      for (int ks = 0; ks < 4; ++ks) {
        short8 ah = *(const short8*)&Ahi[0][wave*16 + ar][ks*32 + ak];
        short8 al = *(const short8*)&Alo[0][wave*16 + ar][ks*32 + ak];
        short8 bh = *(const short8*)&W4F[0][ar][ks*32 + ak];
        short8 bl = *(const short8*)&W4F[1][ar][ks*32 + ak];
        ch = __builtin_amdgcn_mfma_f32_16x16x32_bf16(ah, bh, ch, 0, 0, 0);
        cm = __builtin_amdgcn_mfma_f32_16x16x32_bf16(ah, bl, cm, 0, 0, 0);
        cl = __builtin_amdgcn_mfma_f32_16x16x32_bf16(al, bh, cl, 0, 0, 0);
      }
      const int c = lane & 15;
      const int rbase = wave*16 + (lane >> 4) * 4;
      float esum = 0.f;
      if (c < 2) {
        float b4v = Wsm[640 + c];
#pragma unroll
        for (int r = 0; r < 4; ++r) {
          int row = rbase + r;
          float kval = ch[r] + cm[r] + cl[r] + b4v;
          kS[SLOT][row][c] = kval;
          if constexpr (SLOT == 0) {
            ysL[row][c] = fmaf(heff, CA21 * kval, yL[row][c]);
          } else if constexpr (SLOT == 1) {
            float a = CA31*kS[0][row][c] + CA32*kval;
            ysL[row][c] = fmaf(heff, a, yL[row][c]);
          } else if constexpr (SLOT == 2) {
            float a = CA41*kS[0][row][c] + CA42*kS[1][row][c] + CA43*kval;
            ysL[row][c] = fmaf(heff, a, yL[row][c]);
          } else if constexpr (SLOT == 3) {
            float a = CA51*kS[0][row][c] + CA52*kS[1][row][c] + CA53*kS[2][row][c] + CA54*kval;
            ysL[row][c] = fmaf(heff, a, yL[row][c]);
          } else if constexpr (SLOT == 4) {
            float a = CA61*kS[0][row][c] + CA62*kS[1][row][c] + CA63*kS[2][row][c]
                    + CA64*kS[3][row][c] + CA65*kval;
            ysL[row][c] = fmaf(heff, a, yL[row][c]);
          } else if constexpr (SLOT == 5) {
            float a = CB1*kS[0][row][c] + CB3*kS[2][row][c] + CB4*kS[3][row][c]
                    + CB5*kS[4][row][c] + CB6*kval;
            float y5 = fmaf(heff, a, yL[row][c]);
            y5L[row][c] = y5;
            ysL[row][c] = y5;
          } else if constexpr (SLOT == 6) {
            float e = CE1*kS[0][row][c] + CE3*kS[2][row][c] + CE4*kS[3][row][c]
                    + CE5*kS[4][row][c] + CE6*kS[5][row][c] + CE7*kval;
            e *= heff;
            float tol = 1e-4f + 1e-3f * fmaxf(fabsf(yL[row][c]), fabsf(y5L[row][c]));
            float rr = e / tol;
            esum = fmaf(rr, rr, esum);
          }
        }
      }
      if constexpr (SLOT == 6) {
#pragma unroll
        for (int mk = 1; mk < 64; mk <<= 1) esum += __shfl_xor(esum, mk, 64);
        if (lane == 0) red[wave] = esum;
      }
    }
    __syncthreads();
  };

  // ---- main adaptive loop ----
  for (int iv = 0; iv < 7; ++iv) {
    const float t0 = t_arr[iv], t1 = t_arr[iv + 1];
    float tc = t0;
    for (int s = 0; s < 8; ++s) {
      const int step = iv*8 + s;
      float rem = t1 - tc;
      if (rem <= 1e-9f) break;          // uniform across WGs (identical tc/h everywhere)
      heff = fminf(h, rem);

      if (step == 0) {
        if (tid < 64) ysL[tid >> 1][tid & 1] = yL[tid >> 1][tid & 1];
        __syncthreads();
        feval(IC<0>{});                 // k1 = f(y), fused A21 combine
      } else {
        if (tid < 64) { int m = tid >> 1, c = tid & 1;
          ysL[m][c] = fmaf(heff, CA21 * kS[0][m][c], yL[m][c]); }
        __syncthreads();
      }
      feval(IC<1>{});                   // k2
      feval(IC<2>{});                   // k3
      feval(IC<3>{});                   // k4
      feval(IC<4>{});                   // k5
      feval(IC<5>{});                   // k6 -> y5
      feval(IC<6>{});                   // k7 -> err partials in red[0..1]

      // global controller: deterministic fixed-order reduce + publish
      if (tid == 0) {
        float errsq = red[0] + red[1];
        __hip_atomic_store(&part[wg], errsq, __ATOMIC_RELAXED, __HIP_MEMORY_SCOPE_AGENT);
        u32 old = __hip_atomic_fetch_add(&cnt[step], 1u, __ATOMIC_ACQ_REL, __HIP_MEMORY_SCOPE_AGENT);
        flagL = (old == (u32)(NWG - 1)) ? 1u : 0u;
      }
      __syncthreads();
      if (flagL) {
        red[tid] = __hip_atomic_load(&part[tid], __ATOMIC_RELAXED, __HIP_MEMORY_SCOPE_AGENT);
        __syncthreads();
        for (int st = 128; st >= 1; st >>= 1) {
          if (tid < st) red[tid] += red[tid + st];
          __syncthreads();
        }
        if (tid == 0) {
          float err_norm = sqrtf(red[0] * (1.0f/16384.f));
          bool acc = (err_norm <= 1.0f);
          float factor = fminf(10.f, fmaxf(0.2f, 0.9f * powf(fmaxf(err_norm, 1e-10f), -0.2f)));
          float hn = heff * factor;
          __hip_atomic_store(&hpay[step], hn, __ATOMIC_RELAXED, __HIP_MEMORY_SCOPE_AGENT);
          __hip_atomic_store(&flg[step], acc ? 3u : 1u, __ATOMIC_RELEASE, __HIP_MEMORY_SCOPE_AGENT);
        }
      }
      if (tid == 0) {
        u32 f;
        while ((( f = __hip_atomic_load(&flg[step], __ATOMIC_ACQUIRE, __HIP_MEMORY_SCOPE_AGENT)) & 1u) == 0u)
          __builtin_amdgcn_s_sleep(2);
        bcF = f;
        bcH = __hip_atomic_load(&hpay[step], __ATOMIC_RELAXED, __HIP_MEMORY_SCOPE_AGENT);
      }
      __syncthreads();
      {
        bool acc = (bcF & 2u) != 0u;
        float hn = bcH;
        if (acc) {
          if (tid < 64) { int m = tid >> 1, c = tid & 1;
            yL[m][c] = y5L[m][c];
            kS[0][m][c] = kS[6][m][c];   // FSAL: k1 <- k7
          }
          tc = tc + heff;
        }
        h = hn;
      }
      __syncthreads();
    }
    if (tid < 64)
      out[(size_t)(iv + 1) * 16384 + wg*64 + tid] = yL[tid >> 1][tid & 1];
  }
}

extern "C" void kernel_launch(void* const* d_in, const int* in_sizes, int n_in,
                              void* d_out, int out_size, void* d_ws, size_t ws_size,
                              hipStream_t stream)
{
  const float* x0 = (const float*)d_in[0];
  const float* t  = (const float*)d_in[1];
  const float* W1 = (const float*)d_in[2];
  const float* b1 = (const float*)d_in[3];
  const float* W2 = (const float*)d_in[4];
  const float* b2 = (const float*)d_in[5];
  const float* W3 = (const float*)d_in[6];
  const float* b3 = (const float*)d_in[7];
  const float* W4 = (const float*)d_in[8];
  const float* b4 = (const float*)d_in[9];
  float* out = (float*)d_out;
  float* ws  = (float*)d_ws;

  prologue<<<64, 256, 0, stream>>>(x0, t, W1, b1, W2, b2, W3, b3, W4, b4, ws, out);
  solver<<<NWG, 256, 0, stream>>>(x0, t, ws, out);
}

// Round 4
// 198.777 us; speedup vs baseline: 4.6802x; 1.5018x over previous
//
#include <hip/hip_runtime.h>
#include <stdint.h>

typedef unsigned int u32;
typedef unsigned short u16;
typedef float f32x4 __attribute__((ext_vector_type(4)));
typedef float f32x2 __attribute__((ext_vector_type(2)));
typedef short short8 __attribute__((ext_vector_type(8)));
typedef unsigned short ushort8 __attribute__((ext_vector_type(8)));
typedef unsigned int u32x2 __attribute__((ext_vector_type(2)));
typedef unsigned int u32x4 __attribute__((ext_vector_type(4)));

#define HID  128
#define MT   32        // batch rows per WG
#define NWG  256       // 8192/32, 1 WG per CU -> co-resident
#define NTHR 512       // 8 waves
#define LD   136       // LDS plane stride in u16 (272B rows)

// ---- ws byte offsets ----
#define OFF_PART  0        // 2 x 256 f32 (parity double-buffered)
#define OFF_CNT   2048     // 64 u32
#define OFF_WPACK 4096     // 644 f32: W1(256) b1(128) b2(128) b3(128) b4(2)
#define OFF_W2TH  8192     // 128x128 bf16 [n][k] hi
#define OFF_W2TL  40960
#define OFF_W3TH  73728
#define OFF_W3TL  106496

constexpr float CA21 = (float)(1.0/5.0);
constexpr float CA31 = (float)(3.0/40.0),   CA32 = (float)(9.0/40.0);
constexpr float CA41 = (float)(44.0/45.0),  CA42 = (float)(-56.0/15.0), CA43 = (float)(32.0/9.0);
constexpr float CA51 = (float)(19372.0/6561.0), CA52 = (float)(-25360.0/2187.0);
constexpr float CA53 = (float)(64448.0/6561.0), CA54 = (float)(-212.0/729.0);
constexpr float CA61 = (float)(9017.0/3168.0),  CA62 = (float)(-355.0/33.0);
constexpr float CA63 = (float)(46732.0/5247.0), CA64 = (float)(49.0/176.0), CA65 = (float)(-5103.0/18656.0);
constexpr float CB1 = (float)(35.0/384.0), CB3 = (float)(500.0/1113.0), CB4 = (float)(125.0/192.0);
constexpr float CB5 = (float)(-2187.0/6784.0), CB6 = (float)(11.0/84.0);
constexpr float CE1 = (float)(35.0/384.0 - 5179.0/57600.0);
constexpr float CE3 = (float)(500.0/1113.0 - 7571.0/16695.0);
constexpr float CE4 = (float)(125.0/192.0 - 393.0/640.0);
constexpr float CE5 = (float)(-2187.0/6784.0 + 92097.0/339200.0);
constexpr float CE6 = (float)(11.0/84.0 - 187.0/2100.0);
constexpr float CE7 = (float)(-1.0/40.0);

template<int N> struct IC { static constexpr int v = N; };

__device__ __forceinline__ u16 f2bf(float x) {
  u32 u = __builtin_bit_cast(u32, x);
  u32 r = (u + 0x7FFFu + ((u >> 16) & 1u)) >> 16;
  return (u16)r;
}
__device__ __forceinline__ float bf2f(u16 b) {
  u32 u = ((u32)b) << 16;
  return __builtin_bit_cast(float, u);
}
__device__ __forceinline__ float eluf(float x) {
  return x > 0.f ? x : (__expf(x) - 1.f);
}
// v_cvt_pk_bf16_f32: dst[15:0]=bf16(a), dst[31:16]=bf16(b) (RNE)
__device__ __forceinline__ u32 cvtpk(float a, float b) {
  u32 r; asm("v_cvt_pk_bf16_f32 %0, %1, %2" : "=v"(r) : "v"(a), "v"(b)); return r;
}

// ---------------------------------------------------------------------------
// Prologue
// ---------------------------------------------------------------------------
__global__ void prologue(const float* __restrict__ x0, const float* __restrict__ t,
                         const float* __restrict__ W1, const float* __restrict__ b1,
                         const float* __restrict__ W2, const float* __restrict__ b2,
                         const float* __restrict__ W3, const float* __restrict__ b3,
                         const float* __restrict__ W4, const float* __restrict__ b4,
                         float* __restrict__ ws, float* __restrict__ out)
{
  int gid = blockIdx.x * blockDim.x + threadIdx.x;   // 64*256 = 16384
  out[gid] = x0[gid];
  {
    int k = gid >> 7, j = gid & 127;
    u16* w2th = (u16*)((char*)ws + OFF_W2TH);
    u16* w2tl = (u16*)((char*)ws + OFF_W2TL);
    u16* w3th = (u16*)((char*)ws + OFF_W3TH);
    u16* w3tl = (u16*)((char*)ws + OFF_W3TL);
    float w = W2[gid];
    u16 hb = f2bf(w);
    w2th[j*HID + k] = hb;
    w2tl[j*HID + k] = f2bf(w - bf2f(hb));
    w = W3[gid];
    hb = f2bf(w);
    w3th[j*HID + k] = hb;
    w3tl[j*HID + k] = f2bf(w - bf2f(hb));
  }
  float* wp = ws + OFF_WPACK/4;
  if (gid < 256) wp[gid] = W1[gid];
  if (gid < 128) {
    wp[256 + gid] = b1[gid];
    wp[384 + gid] = b2[gid];
    wp[512 + gid] = b3[gid];
  }
  if (gid < 2)  wp[640 + gid] = b4[gid];
  if (gid < 64) ((u32*)((char*)ws + OFF_CNT))[gid] = 0u;
}

// ---------------------------------------------------------------------------
// Persistent solver: 256 WGs x 512 threads (8 waves), whole adaptive solve.
// ---------------------------------------------------------------------------
__global__ __launch_bounds__(NTHR, 2)
void solver(const float* __restrict__ x0, const float* __restrict__ t_arr,
            const float* __restrict__ W4g, float* __restrict__ ws,
            float* __restrict__ out)
{
  const int tid  = threadIdx.x;
  const int wg   = blockIdx.x;
  const int lane = tid & 63;
  const int wv   = tid >> 6;
  const int nl   = lane & 15;      // MFMA fragment index (n_local / m_local)
  const int g    = lane >> 4;      // k-group

  __shared__ __align__(16) u16 Ahi[2][MT][LD];
  __shared__ __align__(16) u16 Alo[2][MT][LD];
  __shared__ __align__(16) float Wsm[644];
  __shared__ float kS[7][MT][2];
  __shared__ float yL[MT][2];
  __shared__ float y5L[MT][2];
  __shared__ float pD[8][2][16][2];
  __shared__ float red[8];

  // ---- one-time setup ----
  {
    const float* wp = ws + OFF_WPACK/4;
    Wsm[tid] = wp[tid];
    if (tid < 132) Wsm[512 + tid] = wp[512 + tid];
  }
  if (tid < 64) yL[tid >> 1][tid & 1] = x0[wg*64 + tid];

  // resident W2/W3 fragments (A-operand layout: row=n=lane&15, k=g*8+e)
  const u16* w2th = (const u16*)((const char*)ws + OFF_W2TH);
  const u16* w2tl = (const u16*)((const char*)ws + OFF_W2TL);
  const u16* w3th = (const u16*)((const char*)ws + OFF_W3TH);
  const u16* w3tl = (const u16*)((const char*)ws + OFF_W3TL);
  short8 W2H[4], W2L[4], W3H[4], W3L[4];
  {
    const int nglob = wv*16 + nl;
#pragma unroll
    for (int ks = 0; ks < 4; ++ks) {
      int off = nglob*HID + ks*32 + g*8;
      W2H[ks] = *(const short8*)(w2th + off);
      W2L[ks] = *(const short8*)(w2tl + off);
      W3H[ks] = *(const short8*)(w3th + off);
      W3L[ks] = *(const short8*)(w3tl + off);
    }
  }
  // per-lane W4 slice: w4c[r][c] = W4[wv*16+g*4+r][c]
  float w4c[4][2];
#pragma unroll
  for (int r = 0; r < 4; ++r) {
    int n = wv*16 + g*4 + r;
    w4c[r][0] = W4g[n*2 + 0];
    w4c[r][1] = W4g[n*2 + 1];
  }
  __syncthreads();
  const f32x4 bv2 = *(const f32x4*)&Wsm[384 + wv*16 + g*4];
  const f32x4 bv3 = *(const f32x4*)&Wsm[512 + wv*16 + g*4];

  float* part = (float*)((char*)ws + OFF_PART);
  u32*  cnt   = (u32*) ((char*)ws + OFF_CNT);

  float h = 0.5f * (t_arr[1] - t_arr[0]);
  float heff = h;

  // ---- phase A: inline stage combine (from pD) + L1 ----
  auto phaseA = [&](auto SC, int fromPD) {
    constexpr int S = decltype(SC)::v;
    const int m  = tid >> 4;
    const int jc = tid & 15;
    float ys0, ys1;
    const float y0 = yL[m][0], y1 = yL[m][1];
    if constexpr (S == 1) {
      ys0 = y0; ys1 = y1;
    } else {
      const int mt = m >> 4, ml = m & 15;
      float kp0, kp1;
      if (S == 2 && !fromPD) {
        kp0 = kS[0][m][0]; kp1 = kS[0][m][1];
      } else {
        kp0 = Wsm[640]; kp1 = Wsm[641];
#pragma unroll
        for (int w = 0; w < 8; ++w) {
          f32x2 p = *(const f32x2*)&pD[w][mt][ml][0];
          kp0 += p[0]; kp1 += p[1];
        }
        if (jc < 2) kS[S-2][m][jc] = jc ? kp1 : kp0;
      }
      if constexpr (S == 2) {
        ys0 = fmaf(heff, CA21*kp0, y0);
        ys1 = fmaf(heff, CA21*kp1, y1);
      } else if constexpr (S == 3) {
        f32x2 k1 = *(const f32x2*)&kS[0][m][0];
        ys0 = fmaf(heff, CA31*k1[0] + CA32*kp0, y0);
        ys1 = fmaf(heff, CA31*k1[1] + CA32*kp1, y1);
      } else if constexpr (S == 4) {
        f32x2 k1 = *(const f32x2*)&kS[0][m][0];
        f32x2 k2 = *(const f32x2*)&kS[1][m][0];
        ys0 = fmaf(heff, CA41*k1[0] + CA42*k2[0] + CA43*kp0, y0);
        ys1 = fmaf(heff, CA41*k1[1] + CA42*k2[1] + CA43*kp1, y1);
      } else if constexpr (S == 5) {
        f32x2 k1 = *(const f32x2*)&kS[0][m][0];
        f32x2 k2 = *(const f32x2*)&kS[1][m][0];
        f32x2 k3 = *(const f32x2*)&kS[2][m][0];
        ys0 = fmaf(heff, CA51*k1[0] + CA52*k2[0] + CA53*k3[0] + CA54*kp0, y0);
        ys1 = fmaf(heff, CA51*k1[1] + CA52*k2[1] + CA53*k3[1] + CA54*kp1, y1);
      } else if constexpr (S == 6) {
        f32x2 k1 = *(const f32x2*)&kS[0][m][0];
        f32x2 k2 = *(const f32x2*)&kS[1][m][0];
        f32x2 k3 = *(const f32x2*)&kS[2][m][0];
        f32x2 k4 = *(const f32x2*)&kS[3][m][0];
        ys0 = fmaf(heff, CA61*k1[0] + CA62*k2[0] + CA63*k3[0] + CA64*k4[0] + CA65*kp0, y0);
        ys1 = fmaf(heff, CA61*k1[1] + CA62*k2[1] + CA63*k3[1] + CA64*k4[1] + CA65*kp1, y1);
      } else {  // S == 7: y5
        f32x2 k1 = *(const f32x2*)&kS[0][m][0];
        f32x2 k3 = *(const f32x2*)&kS[2][m][0];
        f32x2 k4 = *(const f32x2*)&kS[3][m][0];
        f32x2 k5 = *(const f32x2*)&kS[4][m][0];
        ys0 = fmaf(heff, CB1*k1[0] + CB3*k3[0] + CB4*k4[0] + CB5*k5[0] + CB6*kp0, y0);
        ys1 = fmaf(heff, CB1*k1[1] + CB3*k3[1] + CB4*k4[1] + CB5*k5[1] + CB6*kp1, y1);
        if (jc < 2) y5L[m][jc] = jc ? ys1 : ys0;
      }
    }
    // L1: 8 cols per thread
    const int j0 = jc * 8;
    f32x4 w0a = *(const f32x4*)&Wsm[j0],        w0b = *(const f32x4*)&Wsm[j0 + 4];
    f32x4 w1a = *(const f32x4*)&Wsm[128 + j0],  w1b = *(const f32x4*)&Wsm[128 + j0 + 4];
    f32x4 ba  = *(const f32x4*)&Wsm[256 + j0],  bb  = *(const f32x4*)&Wsm[256 + j0 + 4];
    float v[8];
#pragma unroll
    for (int jj = 0; jj < 4; ++jj)
      v[jj] = eluf(fmaf(ys1, w1a[jj], fmaf(ys0, w0a[jj], ba[jj])));
#pragma unroll
    for (int jj = 0; jj < 4; ++jj)
      v[4+jj] = eluf(fmaf(ys1, w1b[jj], fmaf(ys0, w0b[jj], bb[jj])));
    u32 h01 = cvtpk(v[0], v[1]), h23 = cvtpk(v[2], v[3]);
    u32 h45 = cvtpk(v[4], v[5]), h67 = cvtpk(v[6], v[7]);
    float l0 = v[0] - __builtin_bit_cast(float, h01 << 16);
    float l1 = v[1] - __builtin_bit_cast(float, h01 & 0xffff0000u);
    float l2 = v[2] - __builtin_bit_cast(float, h23 << 16);
    float l3 = v[3] - __builtin_bit_cast(float, h23 & 0xffff0000u);
    float l4 = v[4] - __builtin_bit_cast(float, h45 << 16);
    float l5 = v[5] - __builtin_bit_cast(float, h45 & 0xffff0000u);
    float l6 = v[6] - __builtin_bit_cast(float, h67 << 16);
    float l7 = v[7] - __builtin_bit_cast(float, h67 & 0xffff0000u);
    u32x4 hp = {h01, h23, h45, h67};
    u32x4 lp = {cvtpk(l0,l1), cvtpk(l2,l3), cvtpk(l4,l5), cvtpk(l6,l7)};
    *(u32x4*)&Ahi[0][m][j0] = hp;
    *(u32x4*)&Alo[0][m][j0] = lp;
  };

  // ---- L2: plane0 -> plane1, pack epilogue ----
  auto mmL2 = [&]() {
    f32x4 a0[2], a1[2], a2[2];
#pragma unroll
    for (int mt = 0; mt < 2; ++mt) { a0[mt] = bv2; a1[mt] = {0,0,0,0}; a2[mt] = {0,0,0,0}; }
#pragma unroll
    for (int ks = 0; ks < 4; ++ks) {
#pragma unroll
      for (int mt = 0; mt < 2; ++mt) {
        short8 bh = *(const short8*)&Ahi[0][mt*16 + nl][ks*32 + g*8];
        short8 bl = *(const short8*)&Alo[0][mt*16 + nl][ks*32 + g*8];
        a0[mt] = __builtin_amdgcn_mfma_f32_16x16x32_bf16(W2H[ks], bh, a0[mt], 0, 0, 0);
        a1[mt] = __builtin_amdgcn_mfma_f32_16x16x32_bf16(W2L[ks], bh, a1[mt], 0, 0, 0);
        a2[mt] = __builtin_amdgcn_mfma_f32_16x16x32_bf16(W2H[ks], bl, a2[mt], 0, 0, 0);
      }
    }
    const int n0 = wv*16 + g*4;
#pragma unroll
    for (int mt = 0; mt < 2; ++mt) {
      float v0 = eluf(a0[mt][0] + a1[mt][0] + a2[mt][0]);
      float v1 = eluf(a0[mt][1] + a1[mt][1] + a2[mt][1]);
      float v2 = eluf(a0[mt][2] + a1[mt][2] + a2[mt][2]);
      float v3 = eluf(a0[mt][3] + a1[mt][3] + a2[mt][3]);
      u32 h01 = cvtpk(v0, v1), h23 = cvtpk(v2, v3);
      float l0 = v0 - __builtin_bit_cast(float, h01 << 16);
      float l1 = v1 - __builtin_bit_cast(float, h01 & 0xffff0000u);
      float l2 = v2 - __builtin_bit_cast(float, h23 << 16);
      float l3 = v3 - __builtin_bit_cast(float, h23 & 0xffff0000u);
      u32x2 hp = {h01, h23};
      u32x2 lp = {cvtpk(l0,l1), cvtpk(l2,l3)};
      *(u32x2*)&Ahi[1][mt*16 + nl][n0] = hp;
      *(u32x2*)&Alo[1][mt*16 + nl][n0] = lp;
    }
  };

  // ---- L3 + fused L4 dot -> pD ----
  auto mmL3 = [&]() {
    f32x4 a0[2], a1[2], a2[2];
#pragma unroll
    for (int mt = 0; mt < 2; ++mt) { a0[mt] = bv3; a1[mt] = {0,0,0,0}; a2[mt] = {0,0,0,0}; }
#pragma unroll
    for (int ks = 0; ks < 4; ++ks) {
#pragma unroll
      for (int mt = 0; mt < 2; ++mt) {
        short8 bh = *(const short8*)&Ahi[1][mt*16 + nl][ks*32 + g*8];
        short8 bl = *(const short8*)&Alo[1][mt*16 + nl][ks*32 + g*8];
        a0[mt] = __builtin_amdgcn_mfma_f32_16x16x32_bf16(W3H[ks], bh, a0[mt], 0, 0, 0);
        a1[mt] = __builtin_amdgcn_mfma_f32_16x16x32_bf16(W3L[ks], bh, a1[mt], 0, 0, 0);
        a2[mt] = __builtin_amdgcn_mfma_f32_16x16x32_bf16(W3H[ks], bl, a2[mt], 0, 0, 0);
      }
    }
#pragma unroll
    for (int mt = 0; mt < 2; ++mt) {
      float v0 = eluf(a0[mt][0] + a1[mt][0] + a2[mt][0]);
      float v1 = eluf(a0[mt][1] + a1[mt][1] + a2[mt][1]);
      float v2 = eluf(a0[mt][2] + a1[mt][2] + a2[mt][2]);
      float v3 = eluf(a0[mt][3] + a1[mt][3] + a2[mt][3]);
      float p0 = v0*w4c[0][0] + v1*w4c[1][0] + v2*w4c[2][0] + v3*w4c[3][0];
      float p1 = v0*w4c[0][1] + v1*w4c[1][1] + v2*w4c[2][1] + v3*w4c[3][1];
      p0 += __shfl_xor(p0, 16); p0 += __shfl_xor(p0, 32);
      p1 += __shfl_xor(p1, 16); p1 += __shfl_xor(p1, 32);
      if (lane < 16) {
        f32x2 pp = {p0, p1};
        *(f32x2*)&pD[wv][mt][lane][0] = pp;
      }
    }
  };

  // ---- main adaptive loop ----
  for (int iv = 0; iv < 7; ++iv) {
    const float t1 = t_arr[iv + 1];
    float tc = t_arr[iv];
    for (int s = 0; s < 8; ++s) {
      const int step = iv*8 + s;
      float rem = t1 - tc;
      if (rem <= 1e-9f) break;          // uniform across all WGs
      heff = fminf(h, rem);

      if (iv == 0 && s == 0) {          // fresh k1 eval
        phaseA(IC<1>{}, 0); __syncthreads();
        mmL2(); __syncthreads();
        mmL3(); __syncthreads();
        phaseA(IC<2>{}, 1);
      } else {
        phaseA(IC<2>{}, 0);             // FSAL: k1 = kS[0]
      }
      __syncthreads(); mmL2(); __syncthreads(); mmL3(); __syncthreads();
      phaseA(IC<3>{}, 1); __syncthreads(); mmL2(); __syncthreads(); mmL3(); __syncthreads();
      phaseA(IC<4>{}, 1); __syncthreads(); mmL2(); __syncthreads(); mmL3(); __syncthreads();
      phaseA(IC<5>{}, 1); __syncthreads(); mmL2(); __syncthreads(); mmL3(); __syncthreads();
      phaseA(IC<6>{}, 1); __syncthreads(); mmL2(); __syncthreads(); mmL3(); __syncthreads();
      phaseA(IC<7>{}, 1); __syncthreads(); mmL2(); __syncthreads(); mmL3(); __syncthreads();
      // pD now holds k7 partials

      // ---- error partial (wave 0) + publish ----
      if (wv == 0) {
        int m = lane >> 1, c = lane & 1;
        int emt = m >> 4, eml = m & 15;
        float kp = Wsm[640 + c];
#pragma unroll
        for (int w = 0; w < 8; ++w) kp += pD[w][emt][eml][c];
        kS[6][m][c] = kp;
        float e = heff * (CE1*kS[0][m][c] + CE3*kS[2][m][c] + CE4*kS[3][m][c]
                        + CE5*kS[4][m][c] + CE6*kS[5][m][c] + CE7*kp);
        float tol = 1e-4f + 1e-3f * fmaxf(fabsf(yL[m][c]), fabsf(y5L[m][c]));
        float rr = e / tol;
        float es = rr * rr;
#pragma unroll
        for (int mk = 1; mk < 64; mk <<= 1) es += __shfl_xor(es, mk);
        if (lane == 0) {
          __hip_atomic_store(&part[(step & 1)*256 + wg], es, __ATOMIC_RELAXED, __HIP_MEMORY_SCOPE_AGENT);
          __hip_atomic_fetch_add(&cnt[step], 1u, __ATOMIC_RELEASE, __HIP_MEMORY_SCOPE_AGENT);
        }
      }
      if (tid == 0) {
        while (__hip_atomic_load(&cnt[step], __ATOMIC_ACQUIRE, __HIP_MEMORY_SCOPE_AGENT) < (u32)NWG)
          __builtin_amdgcn_s_sleep(2);
      }
      __syncthreads();
      // ---- symmetric deterministic reduce (every WG, fixed order) ----
      float pv = 0.f;
      if (tid < 256)
        pv = __hip_atomic_load(&part[(step & 1)*256 + tid], __ATOMIC_RELAXED, __HIP_MEMORY_SCOPE_AGENT);
#pragma unroll
      for (int mk = 1; mk < 64; mk <<= 1) pv += __shfl_xor(pv, mk);
      if (tid < 256 && lane == 0) red[wv] = pv;
      __syncthreads();
      float err_norm = sqrtf((red[0] + red[1] + red[2] + red[3]) * (1.0f/16384.f));
      bool acc = (err_norm <= 1.0f);
      float factor = fminf(10.f, fmaxf(0.2f, 0.9f * powf(fmaxf(err_norm, 1e-10f), -0.2f)));
      if (acc) {
        if (tid < 64) { int m = tid >> 1, c = tid & 1;
          yL[m][c] = y5L[m][c];
          kS[0][m][c] = kS[6][m][c];     // FSAL: k1 <- k7
        }
        tc += heff;
      }
      h = heff * factor;
      __syncthreads();
    }
    if (tid < 64)
      out[(size_t)(iv + 1) * 16384 + wg*64 + tid] = yL[tid >> 1][tid & 1];
  }
}

extern "C" void kernel_launch(void* const* d_in, const int* in_sizes, int n_in,
                              void* d_out, int out_size, void* d_ws, size_t ws_size,
                              hipStream_t stream)
{
  const float* x0 = (const float*)d_in[0];
  const float* t  = (const float*)d_in[1];
  const float* W1 = (const float*)d_in[2];
  const float* b1 = (const float*)d_in[3];
  const float* W2 = (const float*)d_in[4];
  const float* b2 = (const float*)d_in[5];
  const float* W3 = (const float*)d_in[6];
  const float* b3 = (const float*)d_in[7];
  const float* W4 = (const float*)d_in[8];
  const float* b4 = (const float*)d_in[9];
  float* out = (float*)d_out;
  float* ws  = (float*)d_ws;

  prologue<<<64, 256, 0, stream>>>(x0, t, W1, b1, W2, b2, W3, b3, W4, b4, ws, out);
  solver<<<NWG, NTHR, 0, stream>>>(x0, t, W4, ws, out);
}